// Round 1
// baseline (2757.768 us; speedup 1.0000x reference)
//
#include <hip/hip_runtime.h>
#include <hip/hip_bf16.h>

#define N_NODES 50000
#define N_EDGES 800000
#define IN_FEAT 512
#define HF 256          // HEADS * OUT_FEAT
#define BM 128
#define BN 128
#define BK 64
#define LDT 72          // padded LDS leading dim (elements)
#define M_PAD 50048     // 391 * 128

typedef short short8 __attribute__((ext_vector_type(8)));
typedef float f32x4 __attribute__((ext_vector_type(4)));

__device__ __forceinline__ unsigned short f2bf(float f) {
    union { float f; unsigned u; } c{f};
    unsigned r = c.u + 0x7FFFu + ((c.u >> 16) & 1u);   // RNE
    return (unsigned short)(r >> 16);
}

// h[M][256] = x[M][512] @ W[256][512]^T  (bf16 MFMA, fp32 accum, fp32 out)
__global__ __launch_bounds__(256) void gemm_kernel(const float* __restrict__ X,
                                                   const float* __restrict__ Wm,
                                                   float* __restrict__ H) {
    __shared__ short As[BM * LDT];
    __shared__ short Bs[BN * LDT];

    const int t    = threadIdx.x;
    const int lane = t & 63;
    const int w    = t >> 6;        // wave 0..3
    const int wr   = w >> 1;        // wave row 0..1 (64 rows each)
    const int wc   = w & 1;         // wave col 0..1 (64 cols each)
    const int brow = blockIdx.x * BM;
    const int bcol = blockIdx.y * BN;

    const int tr = t >> 3;          // 0..31: row group per staging round
    const int tc = (t & 7) * 8;     // 0..56: col start (8 floats per thread)

    f32x4 acc[4][4] = {};

    for (int kt = 0; kt < IN_FEAT; kt += BK) {
        // ---- stage A (x) and B (W) tiles: global fp32 -> bf16 -> LDS ----
        for (int r = 0; r < 4; ++r) {
            const int row = r * 32 + tr;
            {
                int arow = brow + row;
                if (arow >= N_NODES) arow = N_NODES - 1;   // clamp tail
                const float* ga = X + (size_t)arow * IN_FEAT + kt + tc;
                const float4 a0 = *(const float4*)(ga);
                const float4 a1 = *(const float4*)(ga + 4);
                short8 v;
                v[0] = (short)f2bf(a0.x); v[1] = (short)f2bf(a0.y);
                v[2] = (short)f2bf(a0.z); v[3] = (short)f2bf(a0.w);
                v[4] = (short)f2bf(a1.x); v[5] = (short)f2bf(a1.y);
                v[6] = (short)f2bf(a1.z); v[7] = (short)f2bf(a1.w);
                *(short8*)(&As[row * LDT + tc]) = v;
            }
            {
                const float* gb = Wm + (size_t)(bcol + row) * IN_FEAT + kt + tc;
                const float4 b0 = *(const float4*)(gb);
                const float4 b1 = *(const float4*)(gb + 4);
                short8 v;
                v[0] = (short)f2bf(b0.x); v[1] = (short)f2bf(b0.y);
                v[2] = (short)f2bf(b0.z); v[3] = (short)f2bf(b0.w);
                v[4] = (short)f2bf(b1.x); v[5] = (short)f2bf(b1.y);
                v[6] = (short)f2bf(b1.z); v[7] = (short)f2bf(b1.w);
                *(short8*)(&Bs[row * LDT + tc]) = v;
            }
        }
        __syncthreads();

        // ---- compute: 2 k-steps of 32, 16 MFMA each ----
        for (int ks = 0; ks < 2; ++ks) {
            const int koff = ks * 32 + (lane >> 4) * 8;
            short8 a[4], b[4];
#pragma unroll
            for (int m = 0; m < 4; ++m)
                a[m] = *(const short8*)(&As[(wr * 64 + m * 16 + (lane & 15)) * LDT + koff]);
#pragma unroll
            for (int n = 0; n < 4; ++n)
                b[n] = *(const short8*)(&Bs[(wc * 64 + n * 16 + (lane & 15)) * LDT + koff]);
#pragma unroll
            for (int m = 0; m < 4; ++m)
#pragma unroll
                for (int n = 0; n < 4; ++n)
                    acc[m][n] = __builtin_amdgcn_mfma_f32_16x16x32_bf16(a[m], b[n], acc[m][n], 0, 0, 0);
        }
        __syncthreads();
    }

    // ---- write C: col = lane&15, row = (lane>>4)*4 + j ----
#pragma unroll
    for (int m = 0; m < 4; ++m) {
        const int row0 = brow + wr * 64 + m * 16 + (lane >> 4) * 4;
#pragma unroll
        for (int n = 0; n < 4; ++n) {
            const int col = bcol + wc * 64 + n * 16 + (lane & 15);
#pragma unroll
            for (int j = 0; j < 4; ++j) {
                const int row = row0 + j;
                if (row < N_NODES) H[(size_t)row * HF + col] = acc[m][n][j];
            }
        }
    }
}

// one wave per edge (grid-stride): gather h[src], atomicAdd into sum[dst], count dst
__global__ __launch_bounds__(256) void scatter_kernel(const float* __restrict__ h,
                                                      const int* __restrict__ ei,
                                                      float* __restrict__ outsum,
                                                      int* __restrict__ cnt) {
    const int lane   = threadIdx.x & 63;
    const int wave   = (blockIdx.x * blockDim.x + threadIdx.x) >> 6;
    const int nwaves = (gridDim.x * blockDim.x) >> 6;
    for (int e = wave; e < N_EDGES; e += nwaves) {
        const int src = ei[e];
        const int dst = ei[N_EDGES + e];
        const float4 v = *(const float4*)(h + (size_t)src * HF + lane * 4);
        float* o = outsum + (size_t)dst * HF + lane * 4;
        atomicAdd(o + 0, v.x);
        atomicAdd(o + 1, v.y);
        atomicAdd(o + 2, v.z);
        atomicAdd(o + 3, v.w);
        if (lane == 0) atomicAdd(cnt + dst, 1);
    }
}

// out = cnt>0 ? sum/cnt : h   (in place on out, float4 per thread)
__global__ __launch_bounds__(256) void finalize_kernel(const float* __restrict__ h,
                                                       const int* __restrict__ cnt,
                                                       float* __restrict__ out) {
    const size_t i = (size_t)blockIdx.x * blockDim.x + threadIdx.x;
    if (i >= (size_t)N_NODES * (HF / 4)) return;
    const int row = (int)(i >> 6);
    const int c = cnt[row];
    const float4 s = *(const float4*)(out + i * 4);
    const float4 hv = *(const float4*)(h + i * 4);
    float4 r;
    if (c > 0) {
        const float inv = 1.0f / (float)c;
        r.x = s.x * inv; r.y = s.y * inv; r.z = s.z * inv; r.w = s.w * inv;
    } else {
        r = hv;
    }
    *(float4*)(out + i * 4) = r;
}

extern "C" void kernel_launch(void* const* d_in, const int* in_sizes, int n_in,
                              void* d_out, int out_size, void* d_ws, size_t ws_size,
                              hipStream_t stream) {
    const float* x = (const float*)d_in[0];
    const float* W = (const float*)d_in[1];
    const int* ei  = (const int*)d_in[2];
    float* out = (float*)d_out;

    char* ws = (char*)d_ws;
    float* h = (float*)ws;                                    // M_PAD*256*4 = 51.25 MB
    int* cnt = (int*)(ws + (size_t)M_PAD * HF * sizeof(float)); // 200 KB

    hipMemsetAsync(d_out, 0, (size_t)out_size * sizeof(float), stream);
    hipMemsetAsync(cnt, 0, (size_t)N_NODES * sizeof(int), stream);

    dim3 gg(391, 2);
    gemm_kernel<<<gg, dim3(256), 0, stream>>>(x, W, h);

    scatter_kernel<<<8192, 256, 0, stream>>>(h, ei, out, cnt);

    const int fin_threads = N_NODES * (HF / 4);               // 3.2M
    finalize_kernel<<<(fin_threads + 255) / 256, 256, 0, stream>>>(h, cnt, out);
}

// Round 2
// 309.275 us; speedup vs baseline: 8.9169x; 8.9169x over previous
//
#include <hip/hip_runtime.h>
#include <hip/hip_bf16.h>

#define N_NODES 50000
#define N_EDGES 800000
#define IN_FEAT 512
#define HF 256          // HEADS * OUT_FEAT
#define BM 128
#define BN 128
#define BK 64
#define LDT 72          // padded LDS leading dim (elements)

typedef short short8 __attribute__((ext_vector_type(8)));
typedef float f32x4 __attribute__((ext_vector_type(4)));

__device__ __forceinline__ unsigned short f2bf(float f) {
    union { float f; unsigned u; } c{f};
    unsigned r = c.u + 0x7FFFu + ((c.u >> 16) & 1u);   // RNE
    return (unsigned short)(r >> 16);
}

// h[M][256] = x[M][512] @ W[256][512]^T  (bf16 MFMA, fp32 accum, fp32 out)
__global__ __launch_bounds__(256) void gemm_kernel(const float* __restrict__ X,
                                                   const float* __restrict__ Wm,
                                                   float* __restrict__ H) {
    __shared__ short As[BM * LDT];
    __shared__ short Bs[BN * LDT];

    const int t    = threadIdx.x;
    const int lane = t & 63;
    const int w    = t >> 6;        // wave 0..3
    const int wr   = w >> 1;        // wave row 0..1 (64 rows each)
    const int wc   = w & 1;         // wave col 0..1 (64 cols each)
    const int brow = blockIdx.x * BM;
    const int bcol = blockIdx.y * BN;

    const int tr = t >> 3;          // 0..31: row group per staging round
    const int tc = (t & 7) * 8;     // 0..56: col start (8 floats per thread)

    f32x4 acc[4][4] = {};

    for (int kt = 0; kt < IN_FEAT; kt += BK) {
        for (int r = 0; r < 4; ++r) {
            const int row = r * 32 + tr;
            {
                int arow = brow + row;
                if (arow >= N_NODES) arow = N_NODES - 1;   // clamp tail
                const float* ga = X + (size_t)arow * IN_FEAT + kt + tc;
                const float4 a0 = *(const float4*)(ga);
                const float4 a1 = *(const float4*)(ga + 4);
                short8 v;
                v[0] = (short)f2bf(a0.x); v[1] = (short)f2bf(a0.y);
                v[2] = (short)f2bf(a0.z); v[3] = (short)f2bf(a0.w);
                v[4] = (short)f2bf(a1.x); v[5] = (short)f2bf(a1.y);
                v[6] = (short)f2bf(a1.z); v[7] = (short)f2bf(a1.w);
                *(short8*)(&As[row * LDT + tc]) = v;
            }
            {
                const float* gb = Wm + (size_t)(bcol + row) * IN_FEAT + kt + tc;
                const float4 b0 = *(const float4*)(gb);
                const float4 b1 = *(const float4*)(gb + 4);
                short8 v;
                v[0] = (short)f2bf(b0.x); v[1] = (short)f2bf(b0.y);
                v[2] = (short)f2bf(b0.z); v[3] = (short)f2bf(b0.w);
                v[4] = (short)f2bf(b1.x); v[5] = (short)f2bf(b1.y);
                v[6] = (short)f2bf(b1.z); v[7] = (short)f2bf(b1.w);
                *(short8*)(&Bs[row * LDT + tc]) = v;
            }
        }
        __syncthreads();

        for (int ks = 0; ks < 2; ++ks) {
            const int koff = ks * 32 + (lane >> 4) * 8;
            short8 a[4], b[4];
#pragma unroll
            for (int m = 0; m < 4; ++m)
                a[m] = *(const short8*)(&As[(wr * 64 + m * 16 + (lane & 15)) * LDT + koff]);
#pragma unroll
            for (int n = 0; n < 4; ++n)
                b[n] = *(const short8*)(&Bs[(wc * 64 + n * 16 + (lane & 15)) * LDT + koff]);
#pragma unroll
            for (int m = 0; m < 4; ++m)
#pragma unroll
                for (int n = 0; n < 4; ++n)
                    acc[m][n] = __builtin_amdgcn_mfma_f32_16x16x32_bf16(a[m], b[n], acc[m][n], 0, 0, 0);
        }
        __syncthreads();
    }

#pragma unroll
    for (int m = 0; m < 4; ++m) {
        const int row0 = brow + wr * 64 + m * 16 + (lane >> 4) * 4;
#pragma unroll
        for (int n = 0; n < 4; ++n) {
            const int col = bcol + wc * 64 + n * 16 + (lane & 15);
#pragma unroll
            for (int j = 0; j < 4; ++j) {
                const int row = row0 + j;
                if (row < N_NODES) H[(size_t)row * HF + col] = acc[m][n][j];
            }
        }
    }
}

// count in-degree: cursor[dst]++ (int atomics, 800K total)
__global__ __launch_bounds__(256) void count_kernel(const int* __restrict__ ei,
                                                    int* __restrict__ cursor) {
    const int e = blockIdx.x * blockDim.x + threadIdx.x;
    if (e >= N_EDGES) return;
    atomicAdd(&cursor[ei[N_EDGES + e]], 1);
}

// single-block exclusive scan of cursor[] (counts) -> offs[], cursor rewritten to excl
__global__ __launch_bounds__(1024) void scan_kernel(int* __restrict__ cursor,
                                                    int* __restrict__ offs) {
    __shared__ int wsum[16];
    __shared__ int carry;
    const int t = threadIdx.x;           // 0..1023
    const int lane = t & 63, wv = t >> 6;
    if (t == 0) carry = 0;
    __syncthreads();
    for (int base = 0; base < N_NODES; base += 1024) {
        const int i = base + t;
        const int v = (i < N_NODES) ? cursor[i] : 0;
        int s = v;
#pragma unroll
        for (int d = 1; d < 64; d <<= 1) {
            const int u = __shfl_up(s, d, 64);
            if (lane >= d) s += u;
        }
        if (lane == 63) wsum[wv] = s;
        __syncthreads();
        if (wv == 0 && lane < 16) {
            int ws = wsum[lane];
#pragma unroll
            for (int d = 1; d < 16; d <<= 1) {
                const int u = __shfl_up(ws, d, 64);
                if (lane >= d) ws += u;
            }
            wsum[lane] = ws;
        }
        __syncthreads();
        const int wpre = (wv == 0) ? 0 : wsum[wv - 1];
        const int incl = s + wpre + carry;
        const int excl = incl - v;
        if (i < N_NODES) { offs[i] = excl; cursor[i] = excl; }
        __syncthreads();                  // everyone has read carry
        if (t == 1023) carry = incl;
        __syncthreads();
    }
    if (t == 0) offs[N_NODES] = carry;    // = N_EDGES
}

// bucket[pos] = src, pos = cursor[dst]++
__global__ __launch_bounds__(256) void fill_kernel(const int* __restrict__ ei,
                                                   int* __restrict__ cursor,
                                                   int* __restrict__ bucket) {
    const int e = blockIdx.x * blockDim.x + threadIdx.x;
    if (e >= N_EDGES) return;
    const int src = ei[e];
    const int dst = ei[N_EDGES + e];
    const int pos = atomicAdd(&cursor[dst], 1);
    bucket[pos] = src;
}

// one wave per node: sum h[src] rows, divide by count; count==0 -> copy h[node]
__global__ __launch_bounds__(256) void aggregate_kernel(const float* __restrict__ h,
                                                        const int* __restrict__ offs,
                                                        const int* __restrict__ bucket,
                                                        float* __restrict__ out) {
    const int node = (int)(((size_t)blockIdx.x * blockDim.x + threadIdx.x) >> 6);
    const int lane = threadIdx.x & 63;
    if (node >= N_NODES) return;
    const int beg = offs[node];
    const int end = offs[node + 1];
    float4 acc = {0.f, 0.f, 0.f, 0.f};
    for (int i = beg; i < end; ++i) {
        const int src = bucket[i];
        const float4 v = *(const float4*)(h + (size_t)src * HF + lane * 4);
        acc.x += v.x; acc.y += v.y; acc.z += v.z; acc.w += v.w;
    }
    const int c = end - beg;
    float4 r;
    if (c > 0) {
        const float inv = 1.0f / (float)c;
        r.x = acc.x * inv; r.y = acc.y * inv; r.z = acc.z * inv; r.w = acc.w * inv;
    } else {
        r = *(const float4*)(h + (size_t)node * HF + lane * 4);
    }
    *(float4*)(out + (size_t)node * HF + lane * 4) = r;
}

extern "C" void kernel_launch(void* const* d_in, const int* in_sizes, int n_in,
                              void* d_out, int out_size, void* d_ws, size_t ws_size,
                              hipStream_t stream) {
    const float* x = (const float*)d_in[0];
    const float* W = (const float*)d_in[1];
    const int* ei  = (const int*)d_in[2];
    float* out = (float*)d_out;

    char* ws = (char*)d_ws;
    float* h     = (float*)ws;                                  // 50000*256*4 = 51.2 MB
    int* bucket  = (int*)(ws + (size_t)N_NODES * HF * 4);       // 3.2 MB
    int* offs    = (int*)((char*)bucket + (size_t)N_EDGES * 4); // 200 KB
    int* cursor  = (int*)((char*)offs + (size_t)(N_NODES + 1) * 4);

    hipMemsetAsync(cursor, 0, (size_t)N_NODES * sizeof(int), stream);

    dim3 gg(391, 2);
    gemm_kernel<<<gg, dim3(256), 0, stream>>>(x, W, h);

    const int eblocks = (N_EDGES + 255) / 256;
    count_kernel<<<eblocks, 256, 0, stream>>>(ei, cursor);
    scan_kernel<<<1, 1024, 0, stream>>>(cursor, offs);
    fill_kernel<<<eblocks, 256, 0, stream>>>(ei, cursor, bucket);

    aggregate_kernel<<<(N_NODES * 64 + 255) / 256, 256, 0, stream>>>(h, offs, bucket, out);
}

// Round 4
// 203.988 us; speedup vs baseline: 13.5193x; 1.5161x over previous
//
#include <hip/hip_runtime.h>
#include <hip/hip_bf16.h>

#define N_NODES 50000
#define N_EDGES 800000
#define IN_FEAT 512
#define HF 256          // HEADS * OUT_FEAT
#define BM 128
#define BN 256
#define BK 64
#define LDT 72          // padded LDS leading dim (elements)
#define SCAN_BLK 1024
#define NSCAN 49        // ceil(50000/1024)

typedef short short8 __attribute__((ext_vector_type(8)));
typedef unsigned short ushort8 __attribute__((ext_vector_type(8)));
typedef float f32x4 __attribute__((ext_vector_type(4)));

__device__ __forceinline__ unsigned short f2bf(float f) {
    union { float f; unsigned u; } c{f};
    unsigned r = c.u + 0x7FFFu + ((c.u >> 16) & 1u);   // RNE
    return (unsigned short)(r >> 16);
}
__device__ __forceinline__ float bf2f(unsigned short b) {
    union { unsigned u; float f; } c;
    c.u = ((unsigned)b) << 16;
    return c.f;
}

// h[M][256](bf16) = x[M][512] @ W[256][512]^T  (bf16 MFMA, fp32 accum)
__global__ __launch_bounds__(512) void gemm_kernel(const float* __restrict__ X,
                                                   const float* __restrict__ Wm,
                                                   unsigned short* __restrict__ H) {
    __shared__ short As[BM * LDT];
    __shared__ short Bs[BN * LDT];

    const int t    = threadIdx.x;
    const int lane = t & 63;
    const int w    = t >> 6;        // wave 0..7
    const int wr   = w >> 2;        // 0..1 (64 rows)
    const int wc   = w & 3;         // 0..3 (64 cols)
    const int brow = blockIdx.x * BM;

    const int tr = t >> 3;          // 0..63: row per staging round
    const int tc = (t & 7) * 8;     // col start (8 floats)

    f32x4 acc[4][4] = {};

    for (int kt = 0; kt < IN_FEAT; kt += BK) {
        // stage A: 128 rows x 64 cols, 2 rounds
#pragma unroll
        for (int r = 0; r < 2; ++r) {
            const int row = r * 64 + tr;
            int arow = brow + row;
            if (arow >= N_NODES) arow = N_NODES - 1;
            const float* ga = X + (size_t)arow * IN_FEAT + kt + tc;
            const float4 a0 = *(const float4*)(ga);
            const float4 a1 = *(const float4*)(ga + 4);
            short8 v;
            v[0] = (short)f2bf(a0.x); v[1] = (short)f2bf(a0.y);
            v[2] = (short)f2bf(a0.z); v[3] = (short)f2bf(a0.w);
            v[4] = (short)f2bf(a1.x); v[5] = (short)f2bf(a1.y);
            v[6] = (short)f2bf(a1.z); v[7] = (short)f2bf(a1.w);
            *(short8*)(&As[row * LDT + tc]) = v;
        }
        // stage B: 256 rows x 64 cols, 4 rounds
#pragma unroll
        for (int r = 0; r < 4; ++r) {
            const int row = r * 64 + tr;
            const float* gb = Wm + (size_t)row * IN_FEAT + kt + tc;
            const float4 b0 = *(const float4*)(gb);
            const float4 b1 = *(const float4*)(gb + 4);
            short8 v;
            v[0] = (short)f2bf(b0.x); v[1] = (short)f2bf(b0.y);
            v[2] = (short)f2bf(b0.z); v[3] = (short)f2bf(b0.w);
            v[4] = (short)f2bf(b1.x); v[5] = (short)f2bf(b1.y);
            v[6] = (short)f2bf(b1.z); v[7] = (short)f2bf(b1.w);
            *(short8*)(&Bs[row * LDT + tc]) = v;
        }
        __syncthreads();

#pragma unroll
        for (int ks = 0; ks < 2; ++ks) {
            const int koff = ks * 32 + (lane >> 4) * 8;
            short8 a[4], b[4];
#pragma unroll
            for (int m = 0; m < 4; ++m)
                a[m] = *(const short8*)(&As[(wr * 64 + m * 16 + (lane & 15)) * LDT + koff]);
#pragma unroll
            for (int n = 0; n < 4; ++n)
                b[n] = *(const short8*)(&Bs[(wc * 64 + n * 16 + (lane & 15)) * LDT + koff]);
#pragma unroll
            for (int m = 0; m < 4; ++m)
#pragma unroll
                for (int n = 0; n < 4; ++n)
                    acc[m][n] = __builtin_amdgcn_mfma_f32_16x16x32_bf16(a[m], b[n], acc[m][n], 0, 0, 0);
        }
        __syncthreads();
    }

#pragma unroll
    for (int m = 0; m < 4; ++m) {
        const int row0 = brow + wr * 64 + m * 16 + (lane >> 4) * 4;
#pragma unroll
        for (int n = 0; n < 4; ++n) {
            const int col = wc * 64 + n * 16 + (lane & 15);
#pragma unroll
            for (int j = 0; j < 4; ++j) {
                const int row = row0 + j;
                if (row < N_NODES) H[(size_t)row * HF + col] = f2bf(acc[m][n][j]);
            }
        }
    }
}

// in-degree count (int atomics)
__global__ __launch_bounds__(256) void count_kernel(const int* __restrict__ ei,
                                                    int* __restrict__ cursor) {
    const int e = blockIdx.x * blockDim.x + threadIdx.x;
    if (e >= N_EDGES) return;
    atomicAdd(&cursor[ei[N_EDGES + e]], 1);
}

// phase A: per-block (1024 items) local exclusive scan + block total
__global__ __launch_bounds__(256) void scanA_kernel(const int* __restrict__ counts,
                                                    int* __restrict__ offs,
                                                    int* __restrict__ bsum) {
    __shared__ int wtot[4];
    const int t = threadIdx.x;
    const int lane = t & 63, wv = t >> 6;
    const int base = blockIdx.x * SCAN_BLK + t * 4;
    int4 c = {0, 0, 0, 0};
    if (base + 3 < N_NODES) c = *(const int4*)(counts + base);
    else {
        if (base + 0 < N_NODES) c.x = counts[base + 0];
        if (base + 1 < N_NODES) c.y = counts[base + 1];
        if (base + 2 < N_NODES) c.z = counts[base + 2];
        if (base + 3 < N_NODES) c.w = counts[base + 3];
    }
    const int tsum = c.x + c.y + c.z + c.w;
    int s = tsum;
#pragma unroll
    for (int d = 1; d < 64; d <<= 1) {
        const int u = __shfl_up(s, d, 64);
        if (lane >= d) s += u;
    }
    if (lane == 63) wtot[wv] = s;
    __syncthreads();
    int wpre = 0;
    for (int i = 0; i < wv; ++i) wpre += wtot[i];
    const int e0 = wpre + s - tsum;
    if (base + 0 < N_NODES) offs[base + 0] = e0;
    if (base + 1 < N_NODES) offs[base + 1] = e0 + c.x;
    if (base + 2 < N_NODES) offs[base + 2] = e0 + c.x + c.y;
    if (base + 3 < N_NODES) offs[base + 3] = e0 + c.x + c.y + c.z;
    if (t == 255) bsum[blockIdx.x] = wpre + s;   // block total
}

// phase B: exclusive scan of the 49 block totals (one wave)
__global__ __launch_bounds__(64) void scanB_kernel(int* __restrict__ bsum) {
    const int lane = threadIdx.x;
    const int v = (lane < NSCAN) ? bsum[lane] : 0;
    int s = v;
#pragma unroll
    for (int d = 1; d < 64; d <<= 1) {
        const int u = __shfl_up(s, d, 64);
        if (lane >= d) s += u;
    }
    if (lane < NSCAN) bsum[lane] = s - v;
}

// phase C: add block base; emit final offs and a cursor copy for fill
__global__ __launch_bounds__(256) void scanC_kernel(int* __restrict__ offs,
                                                    const int* __restrict__ bsum,
                                                    int* __restrict__ cursor) {
    const int base = blockIdx.x * SCAN_BLK + threadIdx.x * 4;
    if (blockIdx.x == 0 && threadIdx.x == 0) offs[N_NODES] = N_EDGES;
    if (base >= N_NODES) return;
    const int add = bsum[blockIdx.x];
    if (base + 3 < N_NODES) {
        int4 v = *(const int4*)(offs + base);
        v.x += add; v.y += add; v.z += add; v.w += add;
        *(int4*)(offs + base) = v;
        *(int4*)(cursor + base) = v;
    } else {
        for (int k = 0; k < 4 && base + k < N_NODES; ++k) {
            const int v = offs[base + k] + add;
            offs[base + k] = v;
            cursor[base + k] = v;
        }
    }
}

// bucket[pos] = src, pos = cursor[dst]++
__global__ __launch_bounds__(256) void fill_kernel(const int* __restrict__ ei,
                                                   int* __restrict__ cursor,
                                                   int* __restrict__ bucket) {
    const int e = blockIdx.x * blockDim.x + threadIdx.x;
    if (e >= N_EDGES) return;
    const int src = ei[e];
    const int dst = ei[N_EDGES + e];
    const int pos = atomicAdd(&cursor[dst], 1);
    bucket[pos] = src;
}

// one wave per node; lane&31 owns 8 cols (16B bf16), two edges in flight
__global__ __launch_bounds__(256) void aggregate_kernel(const unsigned short* __restrict__ h,
                                                        const int* __restrict__ offs,
                                                        const int* __restrict__ bucket,
                                                        float* __restrict__ out) {
    const int node = (int)(((size_t)blockIdx.x * blockDim.x + threadIdx.x) >> 6);
    const int lane = threadIdx.x & 63;
    if (node >= N_NODES) return;
    const int l32 = lane & 31;
    const int half = lane >> 5;
    const int beg = offs[node];
    const int end = offs[node + 1];
    const int c = end - beg;

    float acc[8] = {0.f, 0.f, 0.f, 0.f, 0.f, 0.f, 0.f, 0.f};
    for (int i = beg + half; i < end; i += 2) {
        const int src = bucket[i];
        const ushort8 v = *(const ushort8*)(h + (size_t)src * HF + l32 * 8);
#pragma unroll
        for (int k = 0; k < 8; ++k) acc[k] += bf2f((unsigned short)v[k]);
    }
    // combine the two half-wave partial sums
#pragma unroll
    for (int k = 0; k < 8; ++k) acc[k] += __shfl_xor(acc[k], 32, 64);

    float4 r;
    if (c > 0) {
        const float inv = 1.0f / (float)c;
        r.x = acc[half * 4 + 0] * inv;
        r.y = acc[half * 4 + 1] * inv;
        r.z = acc[half * 4 + 2] * inv;
        r.w = acc[half * 4 + 3] * inv;
    } else {
        const ushort8 v = *(const ushort8*)(h + (size_t)node * HF + l32 * 8);
        r.x = bf2f((unsigned short)v[half * 4 + 0]);
        r.y = bf2f((unsigned short)v[half * 4 + 1]);
        r.z = bf2f((unsigned short)v[half * 4 + 2]);
        r.w = bf2f((unsigned short)v[half * 4 + 3]);
    }
    // lane l32 owns cols [l32*8, l32*8+8); this half writes its 4-col quarter
    *(float4*)(out + (size_t)node * HF + l32 * 8 + half * 4) = r;
}

extern "C" void kernel_launch(void* const* d_in, const int* in_sizes, int n_in,
                              void* d_out, int out_size, void* d_ws, size_t ws_size,
                              hipStream_t stream) {
    const float* x = (const float*)d_in[0];
    const float* W = (const float*)d_in[1];
    const int* ei  = (const int*)d_in[2];
    float* out = (float*)d_out;

    char* ws = (char*)d_ws;
    unsigned short* h = (unsigned short*)ws;                    // 25.6 MB
    int* bucket = (int*)(ws + (size_t)N_NODES * HF * 2);        // 3.2 MB
    int* offs   = (int*)((char*)bucket + (size_t)N_EDGES * 4);  // 200 KB (+1)
    int* cursor = (int*)((char*)offs + (size_t)(N_NODES + 4) * 4);
    int* bsum   = (int*)((char*)cursor + (size_t)(N_NODES + 4) * 4);

    hipMemsetAsync(cursor, 0, (size_t)N_NODES * sizeof(int), stream);

    gemm_kernel<<<391, 512, 0, stream>>>(x, W, h);

    const int eblocks = (N_EDGES + 255) / 256;
    count_kernel<<<eblocks, 256, 0, stream>>>(ei, cursor);
    scanA_kernel<<<NSCAN, 256, 0, stream>>>(cursor, offs, bsum);
    scanB_kernel<<<1, 64, 0, stream>>>(bsum);
    scanC_kernel<<<NSCAN, 256, 0, stream>>>(offs, bsum, cursor);
    fill_kernel<<<eblocks, 256, 0, stream>>>(ei, cursor, bucket);

    aggregate_kernel<<<(N_NODES * 64 + 255) / 256, 256, 0, stream>>>(h, offs, bucket, out);
}

// Round 5
// 191.842 us; speedup vs baseline: 14.3752x; 1.0633x over previous
//
#include <hip/hip_runtime.h>
#include <hip/hip_bf16.h>

#define N_NODES 50000
#define N_EDGES 800000
#define IN_FEAT 512
#define HF 256          // HEADS * OUT_FEAT
#define BM 128
#define BN 256
#define BK 64
#define LDT 72          // padded LDS leading dim (elements)
#define SCAN_BLK 1024
#define NSCAN 49        // ceil(50000/1024)

typedef short short8 __attribute__((ext_vector_type(8)));
typedef unsigned short ushort8 __attribute__((ext_vector_type(8)));
typedef float f32x4 __attribute__((ext_vector_type(4)));

__device__ __forceinline__ unsigned short f2bf(float f) {
    union { float f; unsigned u; } c{f};
    unsigned r = c.u + 0x7FFFu + ((c.u >> 16) & 1u);   // RNE
    return (unsigned short)(r >> 16);
}
__device__ __forceinline__ float bf2f(unsigned short b) {
    union { unsigned u; float f; } c;
    c.u = ((unsigned)b) << 16;
    return c.f;
}
__device__ __forceinline__ short8 pack8(const float4& a, const float4& b) {
    short8 v;
    v[0] = (short)f2bf(a.x); v[1] = (short)f2bf(a.y);
    v[2] = (short)f2bf(a.z); v[3] = (short)f2bf(a.w);
    v[4] = (short)f2bf(b.x); v[5] = (short)f2bf(b.y);
    v[6] = (short)f2bf(b.z); v[7] = (short)f2bf(b.w);
    return v;
}

// h[M][256](bf16) = x @ W^T, software-pipelined; fused in-degree count
__global__ __launch_bounds__(512) void gemm_kernel(const float* __restrict__ X,
                                                   const float* __restrict__ Wm,
                                                   unsigned short* __restrict__ H,
                                                   const int* __restrict__ ei,
                                                   int* __restrict__ cursor) {
    // ---- fused in-degree count (fire-and-forget int atomics) ----
    {
        const int stride = gridDim.x * blockDim.x;
        for (int e = blockIdx.x * blockDim.x + threadIdx.x; e < N_EDGES; e += stride)
            atomicAdd(&cursor[ei[N_EDGES + e]], 1);
    }

    __shared__ short As[BM * LDT];
    __shared__ short Bs[BN * LDT];

    const int t    = threadIdx.x;
    const int lane = t & 63;
    const int w    = t >> 6;        // wave 0..7
    const int wr   = w >> 2;        // 0..1 (64 rows)
    const int wc   = w & 3;         // 0..3 (64 cols)
    const int brow = blockIdx.x * BM;

    const int tr = t >> 3;          // 0..63: row per staging round
    const int tc = (t & 7) * 8;     // col start (8 floats)

    int arow[2];
#pragma unroll
    for (int r = 0; r < 2; ++r) {
        int a = brow + r * 64 + tr;
        arow[r] = (a >= N_NODES) ? (N_NODES - 1) : a;
    }

    f32x4 acc[4][4] = {};
    float4 rA[2][2], rB[4][2];

    // prologue: load K-tile 0 into registers
#pragma unroll
    for (int r = 0; r < 2; ++r) {
        const float* ga = X + (size_t)arow[r] * IN_FEAT + tc;
        rA[r][0] = *(const float4*)(ga);
        rA[r][1] = *(const float4*)(ga + 4);
    }
#pragma unroll
    for (int r = 0; r < 4; ++r) {
        const float* gb = Wm + (size_t)(r * 64 + tr) * IN_FEAT + tc;
        rB[r][0] = *(const float4*)(gb);
        rB[r][1] = *(const float4*)(gb + 4);
    }

    for (int kti = 0; kti < IN_FEAT / BK; ++kti) {
        // ---- convert + write current regs to LDS ----
#pragma unroll
        for (int r = 0; r < 2; ++r)
            *(short8*)(&As[(r * 64 + tr) * LDT + tc]) = pack8(rA[r][0], rA[r][1]);
#pragma unroll
        for (int r = 0; r < 4; ++r)
            *(short8*)(&Bs[(r * 64 + tr) * LDT + tc]) = pack8(rB[r][0], rB[r][1]);
        __syncthreads();

        // ---- issue next tile's loads (regs free; overlap with MFMA below) ----
        if (kti + 1 < IN_FEAT / BK) {
            const int kn = (kti + 1) * BK;
#pragma unroll
            for (int r = 0; r < 2; ++r) {
                const float* ga = X + (size_t)arow[r] * IN_FEAT + kn + tc;
                rA[r][0] = *(const float4*)(ga);
                rA[r][1] = *(const float4*)(ga + 4);
            }
#pragma unroll
            for (int r = 0; r < 4; ++r) {
                const float* gb = Wm + (size_t)(r * 64 + tr) * IN_FEAT + kn + tc;
                rB[r][0] = *(const float4*)(gb);
                rB[r][1] = *(const float4*)(gb + 4);
            }
        }

        // ---- compute on LDS tiles ----
#pragma unroll
        for (int ks = 0; ks < 2; ++ks) {
            const int koff = ks * 32 + (lane >> 4) * 8;
            short8 a[4], b[4];
#pragma unroll
            for (int m = 0; m < 4; ++m)
                a[m] = *(const short8*)(&As[(wr * 64 + m * 16 + (lane & 15)) * LDT + koff]);
#pragma unroll
            for (int n = 0; n < 4; ++n)
                b[n] = *(const short8*)(&Bs[(wc * 64 + n * 16 + (lane & 15)) * LDT + koff]);
#pragma unroll
            for (int m = 0; m < 4; ++m)
#pragma unroll
                for (int n = 0; n < 4; ++n)
                    acc[m][n] = __builtin_amdgcn_mfma_f32_16x16x32_bf16(a[m], b[n], acc[m][n], 0, 0, 0);
        }
        __syncthreads();
    }

#pragma unroll
    for (int m = 0; m < 4; ++m) {
        const int row0 = brow + wr * 64 + m * 16 + (lane >> 4) * 4;
#pragma unroll
        for (int n = 0; n < 4; ++n) {
            const int col = wc * 64 + n * 16 + (lane & 15);
#pragma unroll
            for (int j = 0; j < 4; ++j) {
                const int row = row0 + j;
                if (row < N_NODES) H[(size_t)row * HF + col] = f2bf(acc[m][n][j]);
            }
        }
    }
}

// phase A: per-block (1024 items) local exclusive scan + block total
__global__ __launch_bounds__(256) void scanA_kernel(const int* __restrict__ counts,
                                                    int* __restrict__ offs,
                                                    int* __restrict__ bsum) {
    __shared__ int wtot[4];
    const int t = threadIdx.x;
    const int lane = t & 63, wv = t >> 6;
    const int base = blockIdx.x * SCAN_BLK + t * 4;
    int4 c = {0, 0, 0, 0};
    if (base + 3 < N_NODES) c = *(const int4*)(counts + base);
    else {
        if (base + 0 < N_NODES) c.x = counts[base + 0];
        if (base + 1 < N_NODES) c.y = counts[base + 1];
        if (base + 2 < N_NODES) c.z = counts[base + 2];
        if (base + 3 < N_NODES) c.w = counts[base + 3];
    }
    const int tsum = c.x + c.y + c.z + c.w;
    int s = tsum;
#pragma unroll
    for (int d = 1; d < 64; d <<= 1) {
        const int u = __shfl_up(s, d, 64);
        if (lane >= d) s += u;
    }
    if (lane == 63) wtot[wv] = s;
    __syncthreads();
    int wpre = 0;
    for (int i = 0; i < wv; ++i) wpre += wtot[i];
    const int e0 = wpre + s - tsum;
    if (base + 0 < N_NODES) offs[base + 0] = e0;
    if (base + 1 < N_NODES) offs[base + 1] = e0 + c.x;
    if (base + 2 < N_NODES) offs[base + 2] = e0 + c.x + c.y;
    if (base + 3 < N_NODES) offs[base + 3] = e0 + c.x + c.y + c.z;
    if (t == 255) bsum[blockIdx.x] = wpre + s;   // block total
}

// phase C: each block re-scans the 49 totals itself, adds base, emits offs+cursor
__global__ __launch_bounds__(256) void scanC_kernel(int* __restrict__ offs,
                                                    const int* __restrict__ bsum,
                                                    int* __restrict__ cursor) {
    __shared__ int pre[NSCAN];
    const int t = threadIdx.x;
    if (t < 64) {
        const int v = (t < NSCAN) ? bsum[t] : 0;
        int s = v;
#pragma unroll
        for (int d = 1; d < 64; d <<= 1) {
            const int u = __shfl_up(s, d, 64);
            if (t >= d) s += u;
        }
        if (t < NSCAN) pre[t] = s - v;   // exclusive
    }
    __syncthreads();
    const int base = blockIdx.x * SCAN_BLK + t * 4;
    if (blockIdx.x == 0 && t == 0) offs[N_NODES] = N_EDGES;
    if (base >= N_NODES) return;
    const int add = pre[blockIdx.x];
    if (base + 3 < N_NODES) {
        int4 v = *(const int4*)(offs + base);
        v.x += add; v.y += add; v.z += add; v.w += add;
        *(int4*)(offs + base) = v;
        *(int4*)(cursor + base) = v;
    } else {
        for (int k = 0; k < 4 && base + k < N_NODES; ++k) {
            const int v = offs[base + k] + add;
            offs[base + k] = v;
            cursor[base + k] = v;
        }
    }
}

// bucket[pos] = src, pos = cursor[dst]++
__global__ __launch_bounds__(256) void fill_kernel(const int* __restrict__ ei,
                                                   int* __restrict__ cursor,
                                                   int* __restrict__ bucket) {
    const int e = blockIdx.x * blockDim.x + threadIdx.x;
    if (e >= N_EDGES) return;
    const int src = ei[e];
    const int dst = ei[N_EDGES + e];
    const int pos = atomicAdd(&cursor[dst], 1);
    bucket[pos] = src;
}

// one wave per node; lane&31 owns 8 cols (16B bf16), two edges in flight
__global__ __launch_bounds__(256) void aggregate_kernel(const unsigned short* __restrict__ h,
                                                        const int* __restrict__ offs,
                                                        const int* __restrict__ bucket,
                                                        float* __restrict__ out) {
    const int node = (int)(((size_t)blockIdx.x * blockDim.x + threadIdx.x) >> 6);
    const int lane = threadIdx.x & 63;
    if (node >= N_NODES) return;
    const int l32 = lane & 31;
    const int half = lane >> 5;
    const int beg = offs[node];
    const int end = offs[node + 1];
    const int c = end - beg;

    float acc[8] = {0.f, 0.f, 0.f, 0.f, 0.f, 0.f, 0.f, 0.f};
    for (int i = beg + half; i < end; i += 2) {
        const int src = bucket[i];
        const ushort8 v = *(const ushort8*)(h + (size_t)src * HF + l32 * 8);
#pragma unroll
        for (int k = 0; k < 8; ++k) acc[k] += bf2f((unsigned short)v[k]);
    }
#pragma unroll
    for (int k = 0; k < 8; ++k) acc[k] += __shfl_xor(acc[k], 32, 64);

    float4 r;
    if (c > 0) {
        const float inv = 1.0f / (float)c;
        r.x = acc[half * 4 + 0] * inv;
        r.y = acc[half * 4 + 1] * inv;
        r.z = acc[half * 4 + 2] * inv;
        r.w = acc[half * 4 + 3] * inv;
    } else {
        const ushort8 v = *(const ushort8*)(h + (size_t)node * HF + l32 * 8);
        r.x = bf2f((unsigned short)v[half * 4 + 0]);
        r.y = bf2f((unsigned short)v[half * 4 + 1]);
        r.z = bf2f((unsigned short)v[half * 4 + 2]);
        r.w = bf2f((unsigned short)v[half * 4 + 3]);
    }
    *(float4*)(out + (size_t)node * HF + l32 * 8 + half * 4) = r;
}

extern "C" void kernel_launch(void* const* d_in, const int* in_sizes, int n_in,
                              void* d_out, int out_size, void* d_ws, size_t ws_size,
                              hipStream_t stream) {
    const float* x = (const float*)d_in[0];
    const float* W = (const float*)d_in[1];
    const int* ei  = (const int*)d_in[2];
    float* out = (float*)d_out;

    char* ws = (char*)d_ws;
    unsigned short* h = (unsigned short*)ws;                    // 25.6 MB
    int* bucket = (int*)(ws + (size_t)N_NODES * HF * 2);        // 3.2 MB
    int* offs   = (int*)((char*)bucket + (size_t)N_EDGES * 4);  // 200 KB (+1)
    int* cursor = (int*)((char*)offs + (size_t)(N_NODES + 4) * 4);
    int* bsum   = (int*)((char*)cursor + (size_t)(N_NODES + 4) * 4);

    hipMemsetAsync(cursor, 0, (size_t)N_NODES * sizeof(int), stream);

    gemm_kernel<<<391, 512, 0, stream>>>(x, W, h, ei, cursor);

    scanA_kernel<<<NSCAN, 256, 0, stream>>>(cursor, offs, bsum);
    scanC_kernel<<<NSCAN, 256, 0, stream>>>(offs, bsum, cursor);

    const int eblocks = (N_EDGES + 255) / 256;
    fill_kernel<<<eblocks, 256, 0, stream>>>(ei, cursor, bucket);

    aggregate_kernel<<<(N_NODES * 64 + 255) / 256, 256, 0, stream>>>(h, offs, bucket, out);
}